// Round 2
// baseline (89.968 us; speedup 1.0000x reference)
//
#include <hip/hip_runtime.h>

// QConv2d v6b: v6 with the nontemporal-store compile fix (clang ext_vector_type
// instead of HIP_vector_type float4 — the builtin requires a native vector type).
// v6 changes vs v5: (a) in-place low-register contractions (peak live ~64+8 floats,
// no scratch spill), (b) lgkm-only raw barriers in strip loop (stores never
// vmcnt-drained in-loop), (c) XOR-swizzled transpose scratch (kills 8-way bank
// conflict on stride-68 b128 reads), (d) nontemporal output stores.
// Structure: grid 256 (1 block/CU = batch), TPB 512, waves 0-3 produce
// W[c1][c2] = (ux (x) uy) rho (ux (x) uy)^T, 4 strips, all 8 waves store each strip.

#define TPB 512

typedef float nfloat4 __attribute__((ext_vector_type(4)));

__global__ __launch_bounds__(TPB, 2) void qconv_fused(
    const float* __restrict__ rho,   // [256][128][128]
    const float* __restrict__ ux,    // [8][8]
    const float* __restrict__ uy,    // [8][8]
    const float* __restrict__ uc,    // [4][4]
    float* __restrict__ out)         // [256][256][256]
{
    __shared__ alignas(16) float L[4][64][68];  // 69632 B

    const int tid  = threadIdx.x;
    const int b    = blockIdx.x;
    const int w    = tid >> 6;
    const int lane = tid & 63;
    const int pyp  = lane >> 3, qyp = lane & 7;   // producer post-transpose identity

    // epilogue work identity: 512 = 16 qg x 2 cs-half x 16 sp-local
    const int qg  = tid & 15;
    const int csh = (tid >> 4) & 1;
    const int spl = tid >> 5;                     // 0..15

    float e0[4], e1[4];
#pragma unroll
    for (int c = 0; c < 4; ++c) { e0[c] = uc[c*4+2]; e1[c] = uc[c*4+3]; }
    float* ob = out + (size_t)b * 65536;

    float X[64];  // single in-place state; producers keep it live through strips

    if (w < 4) {  // producer waves
        const int c1 = w >> 1, c2 = w & 1;
        const int px = lane >> 3, qx = lane & 7;
        const float* rb = rho + (size_t)b * 16384
                        + (size_t)((c1 << 6) + (px << 3)) * 128 + (c2 << 6) + (qx << 3);

        // load X[py][qy]: 16 x b128
#pragma unroll
        for (int py = 0; py < 8; ++py) {
            float4 lo = *(const float4*)(rb + py * 128);
            float4 hi = *(const float4*)(rb + py * 128 + 4);
            X[py*8+0]=lo.x; X[py*8+1]=lo.y; X[py*8+2]=lo.z; X[py*8+3]=lo.w;
            X[py*8+4]=hi.x; X[py*8+5]=hi.y; X[py*8+6]=hi.z; X[py*8+7]=hi.w;
        }

        // Stage A: contract qy (row-local, in-place): X[py][j] = sum_k uy[j][k] X[py][k]
#pragma unroll
        for (int r = 0; r < 8; ++r) {
            float t[8];
#pragma unroll
            for (int j = 0; j < 8; ++j) {
                float a = 0.f;
#pragma unroll
                for (int k = 0; k < 8; ++k) a += uy[j*8+k] * X[r*8+k];
                t[j] = a;
            }
#pragma unroll
            for (int j = 0; j < 8; ++j) X[r*8+j] = t[j];
        }

        // Stage B: contract py (col-local, in-place): X[i][c] = sum_k uy[i][k] X[k][c]
#pragma unroll
        for (int cc = 0; cc < 8; ++cc) {
            float t[8];
#pragma unroll
            for (int i = 0; i < 8; ++i) {
                float a = 0.f;
#pragma unroll
                for (int k = 0; k < 8; ++k) a += uy[i*8+k] * X[k*8+cc];
                t[i] = a;
            }
#pragma unroll
            for (int i = 0; i < 8; ++i) X[i*8+cc] = t[i];
        }

        // wave-private transpose via LDS slice w, XOR-swizzled columns:
        // write row e at col (lane ^ ((e>>3&7)<<2)); read row lane at col (4f ^ ((lane>>3&7)<<2)).
        // Row-stride 68 == 4 (mod 32): swizzle spreads the 8 same-(lane&7) lanes
        // across all 8 bank quads -> conflict-free b128 reads. 16B alignment kept
        // (swizzle only touches bits 2..4 of the float index).
#pragma unroll
        for (int e = 0; e < 64; ++e)
            L[w][e][lane ^ (((e >> 3) & 7) << 2)] = X[e];
        __asm__ volatile("s_waitcnt lgkmcnt(0)" ::: "memory");  // DS in-order per wave
        {
            const int sw = ((lane >> 3) & 7) << 2;
#pragma unroll
            for (int f4 = 0; f4 < 16; ++f4) {
                float4 v = *(const float4*)&L[w][lane][(f4 * 4) ^ sw];
                X[f4*4+0]=v.x; X[f4*4+1]=v.y; X[f4*4+2]=v.z; X[f4*4+3]=v.w;
            }
        }

        // Stage C: contract qx (row-local, in-place): X[p][j] = sum_k ux[j][k] X[p][k]
#pragma unroll
        for (int p = 0; p < 8; ++p) {
            float t[8];
#pragma unroll
            for (int j = 0; j < 8; ++j) {
                float a = 0.f;
#pragma unroll
                for (int k = 0; k < 8; ++k) a += ux[j*8+k] * X[p*8+k];
                t[j] = a;
            }
#pragma unroll
            for (int j = 0; j < 8; ++j) X[p*8+j] = t[j];
        }
    }

    // strip loop: producers finish W rows 2s,2s+1 (Stage D, col-local over X);
    // one lgkm-only barrier per strip; stores are NEVER vmcnt-drained in-loop.
    // Strips hit disjoint LDS rows [16s,16s+16) so W-writes of strip s+1 can't
    // race reads of strip s.
#pragma unroll
    for (int s = 0; s < 4; ++s) {
        if (w < 4) {
#pragma unroll
            for (int i2 = 0; i2 < 2; ++i2) {
                const int i = 2*s + i2;   // px'
#pragma unroll
                for (int j = 0; j < 8; ++j) {
                    float acc = 0.f;
#pragma unroll
                    for (int k = 0; k < 8; ++k) acc += ux[i*8+k] * X[k*8+j];
                    L[w][i*8+pyp][j*8+qyp] = acc;   // plain (unswizzled) W region
                }
            }
        }
        // LDS-visibility barrier only: lgkmcnt(0) (producer ds_writes done) + raw
        // s_barrier. No vmcnt drain -> previous strips' global stores stay in flight.
        // asm "memory" fences on both sides pin LDS ops to their side (rule #18).
        __asm__ volatile("s_waitcnt lgkmcnt(0)" ::: "memory");
        __builtin_amdgcn_s_barrier();
        __asm__ volatile("" ::: "memory");

        const int sp = 16*s + spl;
        float4 wv[4];
#pragma unroll
        for (int ww = 0; ww < 4; ++ww) wv[ww] = *(const float4*)&L[ww][sp][qg * 4];
#pragma unroll
        for (int c = 0; c < 4; ++c) {
#pragma unroll
            for (int cs2 = 0; cs2 < 2; ++cs2) {
                const int cs = 2*csh + cs2;
                const float k00 = e0[c]*e0[cs], k01 = e0[c]*e1[cs];
                const float k10 = e1[c]*e0[cs], k11 = e1[c]*e1[cs];
                nfloat4 v;
                v.x = k00*wv[0].x + k01*wv[1].x + k10*wv[2].x + k11*wv[3].x;
                v.y = k00*wv[0].y + k01*wv[1].y + k10*wv[2].y + k11*wv[3].y;
                v.z = k00*wv[0].z + k01*wv[1].z + k10*wv[2].z + k11*wv[3].z;
                v.w = k00*wv[0].w + k01*wv[1].w + k10*wv[2].w + k11*wv[3].w;
                __builtin_nontemporal_store(v,
                    (nfloat4*)&ob[(size_t)((c*64 + sp) * 256 + cs*64 + qg*4)]);
            }
        }
    }
}

extern "C" void kernel_launch(void* const* d_in, const int* in_sizes, int n_in,
                              void* d_out, int out_size, void* d_ws, size_t ws_size,
                              hipStream_t stream) {
    const float* rho = (const float*)d_in[0];
    const float* ux  = (const float*)d_in[1];
    const float* uy  = (const float*)d_in[2];
    const float* uc  = (const float*)d_in[3];
    float* out = (float*)d_out;
    qconv_fused<<<dim3(256), dim3(TPB), 0, stream>>>(rho, ux, uy, uc, out);
}